// Round 10
// baseline (660.469 us; speedup 1.0000x reference)
//
#include <hip/hip_runtime.h>
#include <hip/hip_bf16.h>

typedef __bf16 bf16_t;
typedef bf16_t bf16x8 __attribute__((ext_vector_type(8)));
typedef float f32x4 __attribute__((ext_vector_type(4)));

__device__ __forceinline__ f32x4 mfma16(bf16x8 a, bf16x8 b, f32x4 c) {
    return __builtin_amdgcn_mfma_f32_16x16x32_bf16(a, b, c, 0, 0, 0);
}

// async 16B/lane global->LDS; lds dest = wave-uniform base, HW adds lane*16
__device__ __forceinline__ void load16_to_lds(const void* g, void* l) {
    __builtin_amdgcn_global_load_lds(
        (__attribute__((address_space(1))) unsigned int*)g,
        (__attribute__((address_space(3))) unsigned int*)l, 16, 0, 0);
}

__device__ __forceinline__ bf16x8 cvt8(f32x4 a, f32x4 b) {
    bf16x8 r;
    r[0] = (bf16_t)a[0]; r[1] = (bf16_t)a[1]; r[2] = (bf16_t)a[2]; r[3] = (bf16_t)a[3];
    r[4] = (bf16_t)b[0]; r[5] = (bf16_t)b[1]; r[6] = (bf16_t)b[2]; r[7] = (bf16_t)b[3];
    return r;
}

// ---------------- fp32 -> bf16 bulk converts -------------------------------
__global__ __launch_bounds__(256)
void cvt_bf16(const float* __restrict__ in, bf16_t* __restrict__ out) {
    const long i = ((long)blockIdx.x * 256 + threadIdx.x) * 8;
    *(bf16x8*)(out + i) = cvt8(*(const f32x4*)(in + i), *(const f32x4*)(in + i + 4));
}

// x (2 slices) + Wq/Wk/Wv in one launch; each slice 2048*2048 elements
__global__ __launch_bounds__(256)
void cvt_all(const float* __restrict__ x,
             const float* __restrict__ Wq, const float* __restrict__ Wk, const float* __restrict__ Wv,
             bf16_t* __restrict__ xb, bf16_t* __restrict__ wqb,
             bf16_t* __restrict__ wkb, bf16_t* __restrict__ wvb) {
    const long NW = 4194304;
    const int y = blockIdx.y;
    const float* s; bf16_t* o;
    if      (y == 0) { s = x;      o = xb;      }
    else if (y == 1) { s = x + NW; o = xb + NW; }
    else if (y == 2) { s = Wq;     o = wqb;     }
    else if (y == 3) { s = Wk;     o = wkb;     }
    else             { s = Wv;     o = wvb;     }
    const long i = ((long)blockIdx.x * 256 + threadIdx.x) * 8;
    *(bf16x8*)(o + i) = cvt8(*(const f32x4*)(s + i), *(const f32x4*)(s + i + 4));
}

// ---------------- QKV projection: all-bf16 m97-style -----------------------
// z=0: q [b,h,s,d] scaled 1/sqrt(128); z=1: k [b,h,s,d]; z=2: vT [b,h,d,s].
__global__ __launch_bounds__(256)
void gemm_qkv(const bf16_t* __restrict__ X,
              const bf16_t* __restrict__ W0, const bf16_t* __restrict__ W1, const bf16_t* __restrict__ W2,
              const float* __restrict__ B0, const float* __restrict__ B1, const float* __restrict__ B2,
              bf16_t* __restrict__ O0, bf16_t* __restrict__ O1, bf16_t* __restrict__ O2)
{
    __shared__ __align__(16) bf16_t As[128 * 32];
    __shared__ __align__(16) bf16_t Bs[128 * 32];
    const int z = blockIdx.z;
    const bf16_t* W = (z == 0) ? W0 : (z == 1 ? W1 : W2);
    const float* Bv = (z == 0) ? B0 : (z == 1 ? B1 : B2);
    bf16_t* O       = (z == 0) ? O0 : (z == 1 ? O1 : O2);

    const int tid = threadIdx.x;
    const int w = tid >> 6, l = tid & 63;
    const int lm = l & 15, lq = l >> 4;
    const long arow0 = (long)blockIdx.y * 128;
    const long brow0 = (long)blockIdx.x * 128;
    const int wm = (w >> 1) * 64, wn = (w & 1) * 64;

    f32x4 acc[4][4] = {};

    for (int kt = 0; kt < 2048; kt += 32) {
#pragma unroll
        for (int i = 0; i < 2; ++i) {
            const int c = w * 128 + i * 64 + l;
            const int row = c >> 2, ce = (c & 3) * 8;
            load16_to_lds(X + (arow0 + row) * 2048 + kt + ce, As + (w * 2 + i) * 512);
            load16_to_lds(W + (brow0 + row) * 2048 + kt + ce, Bs + (w * 2 + i) * 512);
        }
        __syncthreads();
        bf16x8 af[4], bfr[4];
#pragma unroll
        for (int i = 0; i < 4; ++i)
            af[i] = *(const bf16x8*)(As + (wm + i * 16 + lm) * 32 + lq * 8);
#pragma unroll
        for (int j = 0; j < 4; ++j)
            bfr[j] = *(const bf16x8*)(Bs + (wn + j * 16 + lm) * 32 + lq * 8);
#pragma unroll
        for (int i = 0; i < 4; ++i)
#pragma unroll
            for (int j = 0; j < 4; ++j)
                acc[i][j] = mfma16(af[i], bfr[j], acc[i][j]);
        __syncthreads();
    }

    const float scale = (z == 0) ? 0.08838834764831845f : 1.0f;
#pragma unroll
    for (int j = 0; j < 4; ++j) {
        const int col = (int)brow0 + wn + j * 16 + lm;
        const float bb = Bv[col];
        const int h = col >> 7, d = col & 127;
#pragma unroll
        for (int i = 0; i < 4; ++i) {
            const int rbase = (int)arow0 + wm + i * 16 + lq * 4;
#pragma unroll
            for (int r = 0; r < 4; ++r) {
                const int row = rbase + r;
                const int b = row >> 11, s = row & 2047;
                const float v = (acc[i][j][r] + bb) * scale;
                long idx;
                if (z == 2) idx = ((long)(b * 16 + h) * 128 + d) * 2048 + s;   // vT
                else        idx = ((long)(b * 16 + h) * 2048 + s) * 128 + d;   // q,k
                O[idx] = (bf16_t)v;
            }
        }
    }
}

// ---------------- O projection: bf16 cx, bf16 Wo -> fp32 out ---------------
__global__ __launch_bounds__(256)
void gemm_out(const bf16_t* __restrict__ A, const bf16_t* __restrict__ W,
              const float* __restrict__ Bv, float* __restrict__ O)
{
    __shared__ __align__(16) bf16_t As[128 * 32];
    __shared__ __align__(16) bf16_t Bs[128 * 32];

    const int tid = threadIdx.x;
    const int w = tid >> 6, l = tid & 63;
    const int lm = l & 15, lq = l >> 4;
    const long arow0 = (long)blockIdx.y * 128;
    const long brow0 = (long)blockIdx.x * 128;
    const int wm = (w >> 1) * 64, wn = (w & 1) * 64;

    f32x4 acc[4][4] = {};

    for (int kt = 0; kt < 2048; kt += 32) {
#pragma unroll
        for (int i = 0; i < 2; ++i) {
            const int c = w * 128 + i * 64 + l;
            const int row = c >> 2, ce = (c & 3) * 8;
            load16_to_lds(A + (arow0 + row) * 2048 + kt + ce, As + (w * 2 + i) * 512);
            load16_to_lds(W + (brow0 + row) * 2048 + kt + ce, Bs + (w * 2 + i) * 512);
        }
        __syncthreads();
        bf16x8 af[4], bfr[4];
#pragma unroll
        for (int i = 0; i < 4; ++i)
            af[i] = *(const bf16x8*)(As + (wm + i * 16 + lm) * 32 + lq * 8);
#pragma unroll
        for (int j = 0; j < 4; ++j)
            bfr[j] = *(const bf16x8*)(Bs + (wn + j * 16 + lm) * 32 + lq * 8);
#pragma unroll
        for (int i = 0; i < 4; ++i)
#pragma unroll
            for (int j = 0; j < 4; ++j)
                acc[i][j] = mfma16(af[i], bfr[j], acc[i][j]);
        __syncthreads();
    }

#pragma unroll
    for (int j = 0; j < 4; ++j) {
        const int col = (int)brow0 + wn + j * 16 + lm;
        const float bb = Bv[col];
#pragma unroll
        for (int i = 0; i < 4; ++i) {
            const int rbase = (int)arow0 + wm + i * 16 + lq * 4;
#pragma unroll
            for (int r = 0; r < 4; ++r)
                O[(long)(rbase + r) * 2048 + col] = acc[i][j][r] + bb;
        }
    }
}

// ---------------- Flash attention, causal, MFMA ----------------------------
// BQ=64 (1 wave = 16 q rows). Grid 1024, LPT order: heaviest qx first ->
// greedy dispatch approximates longest-first scheduling on any block->CU map.
// Register double-buffer prefetch: tile it+1's K/V global loads issue right
// after staging barrier, overlapping the whole tile-it compute.
// Ks/Vs/Ps XOR-swizzled 16B chunks (0 bank conflicts measured, LDS 40960 B
// -> 4 blocks/CU). P exchange is wave-private: lgkmcnt fence, no barrier.
__global__ __launch_bounds__(256, 4)
void attn(const bf16_t* __restrict__ Q, const bf16_t* __restrict__ K,
          const bf16_t* __restrict__ VT, bf16_t* __restrict__ CTX)
{
    __shared__ __align__(16) bf16_t Ks[64 * 128];   // [kk][d] swizzled
    __shared__ __align__(16) bf16_t Vs[128 * 64];   // [d][s]  swizzled
    __shared__ __align__(16) bf16_t Ps[4][16 * 64]; // per-wave [q][kk] swizzled

    const int tid = threadIdx.x;
    const int w = tid >> 6, l = tid & 63;
    const int lm = l & 15, lq = l >> 4;

    // LPT: qx = 31 - (flat>>5) -> blocks 0..31 are the 32-tile blocks
    const int flat = blockIdx.x;
    const int qx = 31 - (flat >> 5);
    const int bh = flat & 31;

    const int q0 = qx * 64;
    const int qw = q0 + w * 16;      // this wave's 16 q rows
    const long base = (long)bh * 2048 * 128;

    bf16x8 qf[4];
#pragma unroll
    for (int ks = 0; ks < 4; ++ks)
        qf[ks] = *(const bf16x8*)(Q + base + (long)(qw + lm) * 128 + ks * 32 + lq * 8);

    f32x4 ctx[8] = {};
    float mrow[4], lrow[4];
#pragma unroll
    for (int r = 0; r < 4; ++r) { mrow[r] = -1e30f; lrow[r] = 0.f; }

    // prefetch tile 0 into registers
    bf16x8 rk[4], rv[4];
#pragma unroll
    for (int i = 0; i < 4; ++i) {
        const int s = (w * 4 + i) * 64 + l;
        const int kk = s >> 4, dc = (s & 15) ^ (kk & 15);
        rk[i] = *(const bf16x8*)(K + base + (long)kk * 128 + dc * 8);
        const int d = s >> 3, c = (s & 7) ^ (d & 7);
        rv[i] = *(const bf16x8*)(VT + base + (long)d * 2048 + c * 8);
    }

    const int ntiles = qx + 1;
    for (int it = 0; it < ntiles; ++it) {
        const int s0 = it << 6;
        __syncthreads();   // previous tile's Ks/Vs reads complete
#pragma unroll
        for (int i = 0; i < 4; ++i) {
            const int s = (w * 4 + i) * 64 + l;
            *(bf16x8*)(Ks + s * 8) = rk[i];
            *(bf16x8*)(Vs + s * 8) = rv[i];
        }
        __syncthreads();   // staging visible
        // prefetch tile it+1 (overlaps whole compute below)
        if (it + 1 < ntiles) {
            const int s0n = s0 + 64;
#pragma unroll
            for (int i = 0; i < 4; ++i) {
                const int s = (w * 4 + i) * 64 + l;
                const int kk = s >> 4, dc = (s & 15) ^ (kk & 15);
                rk[i] = *(const bf16x8*)(K + base + (long)(s0n + kk) * 128 + dc * 8);
                const int d = s >> 3, c = (s & 7) ^ (d & 7);
                rv[i] = *(const bf16x8*)(VT + base + (long)d * 2048 + s0n + c * 8);
            }
        }

        // S = Q K^T  (C-layout: row=lq*4+r, col=lm)
        f32x4 sc[4] = {};
#pragma unroll
        for (int ks = 0; ks < 4; ++ks)
#pragma unroll
            for (int kj = 0; kj < 4; ++kj) {
                const int kk = kj * 16 + lm;
                const int dc = ks * 4 + lq;
                const bf16x8 kf = *(const bf16x8*)(Ks + (kk * 16 + (dc ^ (kk & 15))) * 8);
                sc[kj] = mfma16(qf[ks], kf, sc[kj]);
            }
        if (s0 + 63 > qw) {   // diagonal tile for this wave
#pragma unroll
            for (int kj = 0; kj < 4; ++kj) {
                const int colg = s0 + kj * 16 + lm;
#pragma unroll
                for (int r = 0; r < 4; ++r) {
                    const int rowg = qw + lq * 4 + r;
                    if (colg > rowg) sc[kj][r] = -1e30f;
                }
            }
        }
        // online softmax (rows live in 16-lane groups)
#pragma unroll
        for (int r = 0; r < 4; ++r) {
            float mx = fmaxf(fmaxf(sc[0][r], sc[1][r]), fmaxf(sc[2][r], sc[3][r]));
#pragma unroll
            for (int off = 1; off < 16; off <<= 1)
                mx = fmaxf(mx, __shfl_xor(mx, off, 64));
            const float mn = fmaxf(mrow[r], mx);
            const float alpha = exp2f((mrow[r] - mn) * 1.4426950408889634f);
            mrow[r] = mn;
            float sum = 0.f;
#pragma unroll
            for (int kj = 0; kj < 4; ++kj) {
                const float p = exp2f((sc[kj][r] - mn) * 1.4426950408889634f);
                sc[kj][r] = p;
                sum += p;
            }
#pragma unroll
            for (int off = 1; off < 16; off <<= 1)
                sum += __shfl_xor(sum, off, 64);
            lrow[r] = lrow[r] * alpha + sum;
#pragma unroll
            for (int dj = 0; dj < 8; ++dj)
                ctx[dj][r] *= alpha;
        }
        // P: C-layout regs -> per-wave swizzled [q][kk] LDS (wave-private)
#pragma unroll
        for (int kj = 0; kj < 4; ++kj)
#pragma unroll
            for (int r = 0; r < 4; ++r) {
                const int q = lq * 4 + r;
                const int kk = kj * 16 + lm;
                Ps[w][q * 64 + ((kk >> 3) ^ (q & 7)) * 8 + (kk & 7)] = (bf16_t)sc[kj][r];
            }
        // wave-private cross-lane exchange: HW DS ops are in-order per wave;
        // the fence stops compiler reordering + waits DS completion.
        __asm__ volatile("s_waitcnt lgkmcnt(0)" ::: "memory");
        // ctx += P @ V
#pragma unroll
        for (int ks2 = 0; ks2 < 2; ++ks2) {
            const int c = ks2 * 4 + lq;
            const bf16x8 pf = *(const bf16x8*)(&Ps[w][0] + lm * 64 + (c ^ (lm & 7)) * 8);
#pragma unroll
            for (int dj = 0; dj < 8; ++dj) {
                const int d = dj * 16 + lm;
                const bf16x8 vf = *(const bf16x8*)(Vs + (d * 8 + (c ^ (d & 7))) * 8);
                ctx[dj] = mfma16(pf, vf, ctx[dj]);
            }
        }
    }

    const int b = bh >> 4, h = bh & 15;
#pragma unroll
    for (int r = 0; r < 4; ++r) {
        const float inv = 1.0f / lrow[r];
        const int s = qw + lq * 4 + r;
#pragma unroll
        for (int dj = 0; dj < 8; ++dj) {
            const int e = h * 128 + dj * 16 + lm;
            CTX[((long)(b * 2048 + s)) * 2048 + e] = (bf16_t)(ctx[dj][r] * inv);
        }
    }
}

extern "C" void kernel_launch(void* const* d_in, const int* in_sizes, int n_in,
                              void* d_out, int out_size, void* d_ws, size_t ws_size,
                              hipStream_t stream)
{
    const float* x  = (const float*)d_in[0];
    const float* Wq = (const float*)d_in[1];
    const float* bq = (const float*)d_in[2];
    const float* Wk = (const float*)d_in[3];
    const float* bk = (const float*)d_in[4];
    const float* Wv = (const float*)d_in[5];
    const float* bv = (const float*)d_in[6];
    const float* Wo = (const float*)d_in[7];
    const float* bo = (const float*)d_in[8];
    float* out = (float*)d_out;

    const size_t NTOK = (size_t)2 * 2048 * 2048;
    const size_t NW   = (size_t)2048 * 2048;
    bf16_t* q  = (bf16_t*)d_ws;       // later reused as wob
    bf16_t* k  = q  + NTOK;
    bf16_t* vT = k  + NTOK;
    bf16_t* cx = vT + NTOK;           // first used as xb
    bf16_t* xb  = cx;
    bf16_t* wob = q;
    // d_out scratch for bf16 QKV weights until gemm_out overwrites it
    bf16_t* wqb = (bf16_t*)d_out;
    bf16_t* wkb = wqb + NW;
    bf16_t* wvb = wkb + NW;

    dim3 blk(256);
    // fp32 -> bf16: x (into cx slot) + Wq/Wk/Wv (into d_out scratch)
    cvt_all<<<dim3(2048, 5), blk, 0, stream>>>(x, Wq, Wk, Wv, xb, wqb, wkb, wvb);
    // QKV projections, all-bf16 m97-style
    gemm_qkv<<<dim3(16, 32, 3), blk, 0, stream>>>(xb, wqb, wkb, wvb, bq, bk, bv, q, k, vT);
    // causal flash attention, LPT-ordered, register-prefetch pipelined
    attn<<<dim3(1024), blk, 0, stream>>>(q, k, vT, cx);
    // Wo -> bf16 into q slot (q dead after attn)
    cvt_bf16<<<dim3(2048), blk, 0, stream>>>(Wo, wob);
    // output projection overwrites d_out scratch with the real output
    gemm_out<<<dim3(16, 32), blk, 0, stream>>>(cx, wob, bo, out);
}

// Round 11
// 417.100 us; speedup vs baseline: 1.5835x; 1.5835x over previous
//
#include <hip/hip_runtime.h>
#include <hip/hip_bf16.h>

typedef __bf16 bf16_t;
typedef bf16_t bf16x8 __attribute__((ext_vector_type(8)));
typedef float f32x4 __attribute__((ext_vector_type(4)));

__device__ __forceinline__ f32x4 mfma16(bf16x8 a, bf16x8 b, f32x4 c) {
    return __builtin_amdgcn_mfma_f32_16x16x32_bf16(a, b, c, 0, 0, 0);
}

// async 16B/lane global->LDS; lds dest = wave-uniform base, HW adds lane*16
__device__ __forceinline__ void load16_to_lds(const void* g, void* l) {
    __builtin_amdgcn_global_load_lds(
        (__attribute__((address_space(1))) unsigned int*)g,
        (__attribute__((address_space(3))) unsigned int*)l, 16, 0, 0);
}

__device__ __forceinline__ bf16x8 cvt8(f32x4 a, f32x4 b) {
    bf16x8 r;
    r[0] = (bf16_t)a[0]; r[1] = (bf16_t)a[1]; r[2] = (bf16_t)a[2]; r[3] = (bf16_t)a[3];
    r[4] = (bf16_t)b[0]; r[5] = (bf16_t)b[1]; r[6] = (bf16_t)b[2]; r[7] = (bf16_t)b[3];
    return r;
}

// ---------------- fp32 -> bf16 bulk converts -------------------------------
__global__ __launch_bounds__(256)
void cvt_bf16(const float* __restrict__ in, bf16_t* __restrict__ out) {
    const long i = ((long)blockIdx.x * 256 + threadIdx.x) * 8;
    *(bf16x8*)(out + i) = cvt8(*(const f32x4*)(in + i), *(const f32x4*)(in + i + 4));
}

// x (2 slices) + Wq/Wk/Wv in one launch; each slice 2048*2048 elements
__global__ __launch_bounds__(256)
void cvt_all(const float* __restrict__ x,
             const float* __restrict__ Wq, const float* __restrict__ Wk, const float* __restrict__ Wv,
             bf16_t* __restrict__ xb, bf16_t* __restrict__ wqb,
             bf16_t* __restrict__ wkb, bf16_t* __restrict__ wvb) {
    const long NW = 4194304;
    const int y = blockIdx.y;
    const float* s; bf16_t* o;
    if      (y == 0) { s = x;      o = xb;      }
    else if (y == 1) { s = x + NW; o = xb + NW; }
    else if (y == 2) { s = Wq;     o = wqb;     }
    else if (y == 3) { s = Wk;     o = wkb;     }
    else             { s = Wv;     o = wvb;     }
    const long i = ((long)blockIdx.x * 256 + threadIdx.x) * 8;
    *(bf16x8*)(o + i) = cvt8(*(const f32x4*)(s + i), *(const f32x4*)(s + i + 4));
}

// ---------------- QKV projection: all-bf16 m97-style -----------------------
// z=0: q [b,h,s,d] scaled 1/sqrt(128); z=1: k [b,h,s,d]; z=2: vT [b,h,d,s].
__global__ __launch_bounds__(256)
void gemm_qkv(const bf16_t* __restrict__ X,
              const bf16_t* __restrict__ W0, const bf16_t* __restrict__ W1, const bf16_t* __restrict__ W2,
              const float* __restrict__ B0, const float* __restrict__ B1, const float* __restrict__ B2,
              bf16_t* __restrict__ O0, bf16_t* __restrict__ O1, bf16_t* __restrict__ O2)
{
    __shared__ __align__(16) bf16_t As[128 * 32];
    __shared__ __align__(16) bf16_t Bs[128 * 32];
    const int z = blockIdx.z;
    const bf16_t* W = (z == 0) ? W0 : (z == 1 ? W1 : W2);
    const float* Bv = (z == 0) ? B0 : (z == 1 ? B1 : B2);
    bf16_t* O       = (z == 0) ? O0 : (z == 1 ? O1 : O2);

    const int tid = threadIdx.x;
    const int w = tid >> 6, l = tid & 63;
    const int lm = l & 15, lq = l >> 4;
    const long arow0 = (long)blockIdx.y * 128;
    const long brow0 = (long)blockIdx.x * 128;
    const int wm = (w >> 1) * 64, wn = (w & 1) * 64;

    f32x4 acc[4][4] = {};

    for (int kt = 0; kt < 2048; kt += 32) {
#pragma unroll
        for (int i = 0; i < 2; ++i) {
            const int c = w * 128 + i * 64 + l;
            const int row = c >> 2, ce = (c & 3) * 8;
            load16_to_lds(X + (arow0 + row) * 2048 + kt + ce, As + (w * 2 + i) * 512);
            load16_to_lds(W + (brow0 + row) * 2048 + kt + ce, Bs + (w * 2 + i) * 512);
        }
        __syncthreads();
        bf16x8 af[4], bfr[4];
#pragma unroll
        for (int i = 0; i < 4; ++i)
            af[i] = *(const bf16x8*)(As + (wm + i * 16 + lm) * 32 + lq * 8);
#pragma unroll
        for (int j = 0; j < 4; ++j)
            bfr[j] = *(const bf16x8*)(Bs + (wn + j * 16 + lm) * 32 + lq * 8);
#pragma unroll
        for (int i = 0; i < 4; ++i)
#pragma unroll
            for (int j = 0; j < 4; ++j)
                acc[i][j] = mfma16(af[i], bfr[j], acc[i][j]);
        __syncthreads();
    }

    const float scale = (z == 0) ? 0.08838834764831845f : 1.0f;
#pragma unroll
    for (int j = 0; j < 4; ++j) {
        const int col = (int)brow0 + wn + j * 16 + lm;
        const float bb = Bv[col];
        const int h = col >> 7, d = col & 127;
#pragma unroll
        for (int i = 0; i < 4; ++i) {
            const int rbase = (int)arow0 + wm + i * 16 + lq * 4;
#pragma unroll
            for (int r = 0; r < 4; ++r) {
                const int row = rbase + r;
                const int b = row >> 11, s = row & 2047;
                const float v = (acc[i][j][r] + bb) * scale;
                long idx;
                if (z == 2) idx = ((long)(b * 16 + h) * 128 + d) * 2048 + s;   // vT
                else        idx = ((long)(b * 16 + h) * 2048 + s) * 128 + d;   // q,k
                O[idx] = (bf16_t)v;
            }
        }
    }
}

// ---------------- O projection: bf16 cx, bf16 Wo -> fp32 out ---------------
__global__ __launch_bounds__(256)
void gemm_out(const bf16_t* __restrict__ A, const bf16_t* __restrict__ W,
              const float* __restrict__ Bv, float* __restrict__ O)
{
    __shared__ __align__(16) bf16_t As[128 * 32];
    __shared__ __align__(16) bf16_t Bs[128 * 32];

    const int tid = threadIdx.x;
    const int w = tid >> 6, l = tid & 63;
    const int lm = l & 15, lq = l >> 4;
    const long arow0 = (long)blockIdx.y * 128;
    const long brow0 = (long)blockIdx.x * 128;
    const int wm = (w >> 1) * 64, wn = (w & 1) * 64;

    f32x4 acc[4][4] = {};

    for (int kt = 0; kt < 2048; kt += 32) {
#pragma unroll
        for (int i = 0; i < 2; ++i) {
            const int c = w * 128 + i * 64 + l;
            const int row = c >> 2, ce = (c & 3) * 8;
            load16_to_lds(A + (arow0 + row) * 2048 + kt + ce, As + (w * 2 + i) * 512);
            load16_to_lds(W + (brow0 + row) * 2048 + kt + ce, Bs + (w * 2 + i) * 512);
        }
        __syncthreads();
        bf16x8 af[4], bfr[4];
#pragma unroll
        for (int i = 0; i < 4; ++i)
            af[i] = *(const bf16x8*)(As + (wm + i * 16 + lm) * 32 + lq * 8);
#pragma unroll
        for (int j = 0; j < 4; ++j)
            bfr[j] = *(const bf16x8*)(Bs + (wn + j * 16 + lm) * 32 + lq * 8);
#pragma unroll
        for (int i = 0; i < 4; ++i)
#pragma unroll
            for (int j = 0; j < 4; ++j)
                acc[i][j] = mfma16(af[i], bfr[j], acc[i][j]);
        __syncthreads();
    }

#pragma unroll
    for (int j = 0; j < 4; ++j) {
        const int col = (int)brow0 + wn + j * 16 + lm;
        const float bb = Bv[col];
#pragma unroll
        for (int i = 0; i < 4; ++i) {
            const int rbase = (int)arow0 + wm + i * 16 + lq * 4;
#pragma unroll
            for (int r = 0; r < 4; ++r)
                O[(long)(rbase + r) * 2048 + col] = acc[i][j][r] + bb;
        }
    }
}

// ---------------- Flash attention, causal, MFMA ----------------------------
// BQ=64 (1 wave = 16 q rows). LDS DOUBLE-BUFFERED K/V staged by
// global_load_lds (no VGPR footprint -> no spill): one barrier per tile;
// prefetch for tile it+1 issues right after the barrier and has the whole
// tile-it compute to land (drained by the next barrier's vmcnt wait).
// LDS = 2*(16K+16K) + 8K = 72 KB -> 2 blocks/CU. XOR-swizzled chunks
// (0 bank conflicts, measured r9). LPT block order: heaviest qx first.
__global__ __launch_bounds__(256, 2)
void attn(const bf16_t* __restrict__ Q, const bf16_t* __restrict__ K,
          const bf16_t* __restrict__ VT, bf16_t* __restrict__ CTX)
{
    __shared__ __align__(16) bf16_t Ks[2][64 * 128];   // [kk][d] swizzled
    __shared__ __align__(16) bf16_t Vs[2][128 * 64];   // [d][s]  swizzled
    __shared__ __align__(16) bf16_t Ps[4][16 * 64];    // per-wave [q][kk] swizzled

    const int tid = threadIdx.x;
    const int w = tid >> 6, l = tid & 63;
    const int lm = l & 15, lq = l >> 4;

    // LPT: qx = 31 - (flat>>5)
    const int flat = blockIdx.x;
    const int qx = 31 - (flat >> 5);
    const int bh = flat & 31;

    const int q0 = qx * 64;
    const int qw = q0 + w * 16;      // this wave's 16 q rows
    const long base = (long)bh * 2048 * 128;

    bf16x8 qf[4];
#pragma unroll
    for (int ks = 0; ks < 4; ++ks)
        qf[ks] = *(const bf16x8*)(Q + base + (long)(qw + lm) * 128 + ks * 32 + lq * 8);

    f32x4 ctx[8] = {};
    float mrow[4], lrow[4];
#pragma unroll
    for (int r = 0; r < 4; ++r) { mrow[r] = -1e30f; lrow[r] = 0.f; }

    // stage tile 0 into buffer 0 (async DMA, no VGPRs)
#pragma unroll
    for (int i = 0; i < 4; ++i) {
        const int s = (w * 4 + i) * 64 + l;
        const int kk = s >> 4, dc = (s & 15) ^ (kk & 15);
        load16_to_lds(K + base + (long)kk * 128 + dc * 8, Ks[0] + (w * 4 + i) * 512);
        const int d = s >> 3, c = (s & 7) ^ (d & 7);
        load16_to_lds(VT + base + (long)d * 2048 + c * 8, Vs[0] + (w * 4 + i) * 512);
    }

    const int ntiles = qx + 1;
    for (int it = 0; it < ntiles; ++it) {
        const int s0 = it << 6;
        const int buf = it & 1;
        __syncthreads();   // vmcnt drained: buf staged; prev reads of buf^1 done

        // prefetch tile it+1 into the other buffer (overlaps all compute below)
        if (it + 1 < ntiles) {
            const int s0n = s0 + 64;
#pragma unroll
            for (int i = 0; i < 4; ++i) {
                const int s = (w * 4 + i) * 64 + l;
                const int kk = s >> 4, dc = (s & 15) ^ (kk & 15);
                load16_to_lds(K + base + (long)(s0n + kk) * 128 + dc * 8,
                              Ks[buf ^ 1] + (w * 4 + i) * 512);
                const int d = s >> 3, c = (s & 7) ^ (d & 7);
                load16_to_lds(VT + base + (long)d * 2048 + s0n + c * 8,
                              Vs[buf ^ 1] + (w * 4 + i) * 512);
            }
        }

        // S = Q K^T  (C-layout: row=lq*4+r, col=lm)
        f32x4 sc[4] = {};
#pragma unroll
        for (int ks = 0; ks < 4; ++ks)
#pragma unroll
            for (int kj = 0; kj < 4; ++kj) {
                const int kk = kj * 16 + lm;
                const int dc = ks * 4 + lq;
                const bf16x8 kf = *(const bf16x8*)(Ks[buf] + (kk * 16 + (dc ^ (kk & 15))) * 8);
                sc[kj] = mfma16(qf[ks], kf, sc[kj]);
            }
        if (s0 + 63 > qw) {   // diagonal tile for this wave
#pragma unroll
            for (int kj = 0; kj < 4; ++kj) {
                const int colg = s0 + kj * 16 + lm;
#pragma unroll
                for (int r = 0; r < 4; ++r) {
                    const int rowg = qw + lq * 4 + r;
                    if (colg > rowg) sc[kj][r] = -1e30f;
                }
            }
        }
        // online softmax (rows live in 16-lane groups)
#pragma unroll
        for (int r = 0; r < 4; ++r) {
            float mx = fmaxf(fmaxf(sc[0][r], sc[1][r]), fmaxf(sc[2][r], sc[3][r]));
#pragma unroll
            for (int off = 1; off < 16; off <<= 1)
                mx = fmaxf(mx, __shfl_xor(mx, off, 64));
            const float mn = fmaxf(mrow[r], mx);
            const float alpha = exp2f((mrow[r] - mn) * 1.4426950408889634f);
            mrow[r] = mn;
            float sum = 0.f;
#pragma unroll
            for (int kj = 0; kj < 4; ++kj) {
                const float p = exp2f((sc[kj][r] - mn) * 1.4426950408889634f);
                sc[kj][r] = p;
                sum += p;
            }
#pragma unroll
            for (int off = 1; off < 16; off <<= 1)
                sum += __shfl_xor(sum, off, 64);
            lrow[r] = lrow[r] * alpha + sum;
#pragma unroll
            for (int dj = 0; dj < 8; ++dj)
                ctx[dj][r] *= alpha;
        }
        // P: C-layout regs -> per-wave swizzled [q][kk] LDS (wave-private)
#pragma unroll
        for (int kj = 0; kj < 4; ++kj)
#pragma unroll
            for (int r = 0; r < 4; ++r) {
                const int q = lq * 4 + r;
                const int kk = kj * 16 + lm;
                Ps[w][q * 64 + ((kk >> 3) ^ (q & 7)) * 8 + (kk & 7)] = (bf16_t)sc[kj][r];
            }
        // wave-private cross-lane exchange: per-wave DS ops are in-order;
        // fence stops compiler reordering + waits DS completion.
        __asm__ volatile("s_waitcnt lgkmcnt(0)" ::: "memory");
        // ctx += P @ V
#pragma unroll
        for (int ks2 = 0; ks2 < 2; ++ks2) {
            const int c = ks2 * 4 + lq;
            const bf16x8 pf = *(const bf16x8*)(&Ps[w][0] + lm * 64 + (c ^ (lm & 7)) * 8);
#pragma unroll
            for (int dj = 0; dj < 8; ++dj) {
                const int d = dj * 16 + lm;
                const bf16x8 vf = *(const bf16x8*)(Vs[buf] + (d * 8 + (c ^ (d & 7))) * 8);
                ctx[dj] = mfma16(pf, vf, ctx[dj]);
            }
        }
    }

    const int b = bh >> 4, h = bh & 15;
#pragma unroll
    for (int r = 0; r < 4; ++r) {
        const float inv = 1.0f / lrow[r];
        const int s = qw + lq * 4 + r;
#pragma unroll
        for (int dj = 0; dj < 8; ++dj) {
            const int e = h * 128 + dj * 16 + lm;
            CTX[((long)(b * 2048 + s)) * 2048 + e] = (bf16_t)(ctx[dj][r] * inv);
        }
    }
}

extern "C" void kernel_launch(void* const* d_in, const int* in_sizes, int n_in,
                              void* d_out, int out_size, void* d_ws, size_t ws_size,
                              hipStream_t stream)
{
    const float* x  = (const float*)d_in[0];
    const float* Wq = (const float*)d_in[1];
    const float* bq = (const float*)d_in[2];
    const float* Wk = (const float*)d_in[3];
    const float* bk = (const float*)d_in[4];
    const float* Wv = (const float*)d_in[5];
    const float* bv = (const float*)d_in[6];
    const float* Wo = (const float*)d_in[7];
    const float* bo = (const float*)d_in[8];
    float* out = (float*)d_out;

    const size_t NTOK = (size_t)2 * 2048 * 2048;
    const size_t NW   = (size_t)2048 * 2048;
    bf16_t* q  = (bf16_t*)d_ws;       // later reused as wob
    bf16_t* k  = q  + NTOK;
    bf16_t* vT = k  + NTOK;
    bf16_t* cx = vT + NTOK;           // first used as xb
    bf16_t* xb  = cx;
    bf16_t* wob = q;
    // d_out scratch for bf16 QKV weights until gemm_out overwrites it
    bf16_t* wqb = (bf16_t*)d_out;
    bf16_t* wkb = wqb + NW;
    bf16_t* wvb = wkb + NW;

    dim3 blk(256);
    // fp32 -> bf16: x (into cx slot) + Wq/Wk/Wv (into d_out scratch)
    cvt_all<<<dim3(2048, 5), blk, 0, stream>>>(x, Wq, Wk, Wv, xb, wqb, wkb, wvb);
    // QKV projections, all-bf16 m97-style
    gemm_qkv<<<dim3(16, 32, 3), blk, 0, stream>>>(xb, wqb, wkb, wvb, bq, bk, bv, q, k, vT);
    // causal flash attention, LDS-double-buffered, LPT-ordered
    attn<<<dim3(1024), blk, 0, stream>>>(q, k, vT, cx);
    // Wo -> bf16 into q slot (q dead after attn)
    cvt_bf16<<<dim3(2048), blk, 0, stream>>>(Wo, wob);
    // output projection overwrites d_out scratch with the real output
    gemm_out<<<dim3(16, 32), blk, 0, stream>>>(cx, wob, bo, out);
}